// Round 5
// baseline (424.903 us; speedup 1.0000x reference)
//
#include <hip/hip_runtime.h>
#include <math.h>

#define D_DIM 4096
#define E_DIM 64
#define TM 32                    // tokens per block (32/wave, 2 M-tiles of 16)
#define CHK 64                   // k per chunk
#define KQ 1024                  // k per wave (in-block k-split by 4 waves)
#define NCH (KQ / CHK)           // 16 chunks per wave

typedef __attribute__((ext_vector_type(8))) short bf16x8;
typedef __attribute__((ext_vector_type(4))) short s16x4;
typedef __attribute__((ext_vector_type(4))) float f32x4;

// ---------------- kernel 0: split W (fp32) into 3 exact bf16 levels ----------------
__global__ __launch_bounds__(256) void presplit(
    const float* __restrict__ W,
    short* __restrict__ wh, short* __restrict__ wm, short* __restrict__ wl)
{
    const int i = (blockIdx.x * 256 + threadIdx.x) * 4;
    const f32x4 v = *(const f32x4*)&W[i];
    s16x4 h, m, l;
    #pragma unroll
    for (int j = 0; j < 4; ++j) {
        const uint u  = __float_as_uint(v[j]);
        const uint hh = u & 0xFFFF0000u;
        const float r  = v[j] - __uint_as_float(hh);   // exact residual
        const uint mm = __float_as_uint(r) & 0xFFFF0000u;
        const float r2 = r - __uint_as_float(mm);      // exact residual
        h[j] = (short)(hh >> 16);
        m[j] = (short)(mm >> 16);
        l[j] = (short)(__float_as_uint(r2) >> 16);
    }
    *(s16x4*)&wh[i] = h;
    *(s16x4*)&wm[i] = m;
    *(s16x4*)&wl[i] = l;
}

// in-register 3-level split of 8 fp32 (one A fragment)
__device__ inline void split3(const f32x4 a0, const f32x4 a1,
                              bf16x8& fh, bf16x8& fm, bf16x8& fl) {
    uint uh[8], um[8], ul[8];
    float f[8] = {a0[0], a0[1], a0[2], a0[3], a1[0], a1[1], a1[2], a1[3]};
    #pragma unroll
    for (int j = 0; j < 8; ++j) {
        const uint u = __float_as_uint(f[j]);
        const uint h = u & 0xFFFF0000u;
        const float r = f[j] - __uint_as_float(h);
        const uint m = __float_as_uint(r) & 0xFFFF0000u;
        const float r2 = r - __uint_as_float(m);
        uh[j] = h; um[j] = m; ul[j] = __float_as_uint(r2);
    }
    union { bf16x8 v; uint u[4]; } H, M, L;
    #pragma unroll
    for (int j = 0; j < 4; ++j) {
        H.u[j] = (uh[2*j] >> 16) | (uh[2*j+1] & 0xFFFF0000u);
        M.u[j] = (um[2*j] >> 16) | (um[2*j+1] & 0xFFFF0000u);
        L.u[j] = (ul[2*j] >> 16) | (ul[2*j+1] & 0xFFFF0000u);
    }
    fh = H.v; fm = M.v; fl = L.v;
}

// ---------------- kernel 1: fused router — barrier-free MFMA K-loop ----------------
__global__ __launch_bounds__(256) void router_main(
    const float* __restrict__ hs,
    const short* __restrict__ wh,
    const short* __restrict__ wm,
    const short* __restrict__ wl,
    const float* __restrict__ bias,
    float* __restrict__ out,
    int nTok)
{
    __shared__ float red[4][TM][E_DIM];    // 32 KB partial logits per wave
    __shared__ float fin[TM * E_DIM];      // 8 KB reduced logits (flat)
    __shared__ float s_m[TM], s_inv[TM];

    const int tid  = threadIdx.x;
    const int lane = tid & 63;
    const int w    = tid >> 6;             // wave id = k-quarter
    const int tb   = blockIdx.x * TM;
    const int l15  = lane & 15;
    const int lq   = lane >> 4;
    const int kb   = w * KQ;

    // A fragments direct from global: lane -> A[m=l15][k=lq*8+j]
    const float* a0 = hs + (size_t)(tb + l15) * D_DIM + kb + lq * 8;
    const float* a1 = a0 + (size_t)16 * D_DIM;

    f32x4 acc[2][4];
    #pragma unroll
    for (int m = 0; m < 2; ++m)
        #pragma unroll
        for (int t = 0; t < 4; ++t)
            acc[m][t] = (f32x4){0.f, 0.f, 0.f, 0.f};

    f32x4 ca[2][4], pa[2][4];

    auto loadA = [&](int ch, f32x4 (*dst)[4]) {
        #pragma unroll
        for (int m = 0; m < 2; ++m) {
            const float* p = (m ? a1 : a0) + ch * CHK;
            dst[m][0] = *(const f32x4*)(p);
            dst[m][1] = *(const f32x4*)(p + 4);
            dst[m][2] = *(const f32x4*)(p + 32);
            dst[m][3] = *(const f32x4*)(p + 36);
        }
    };

    auto compute = [&](int ch, f32x4 (*a)[4]) {
        const size_t kk = (size_t)kb + ch * CHK;
        #pragma unroll
        for (int s = 0; s < 2; ++s) {
            bf16x8 ah0, am0, al0, ah1, am1, al1;
            split3(a[0][2*s], a[0][2*s+1], ah0, am0, al0);
            split3(a[1][2*s], a[1][2*s+1], ah1, am1, al1);
            #pragma unroll
            for (int t = 0; t < 4; ++t) {
                const size_t wb = (size_t)(t * 16 + l15) * D_DIM + kk + s * 32 + lq * 8;
                const bf16x8 bh = *(const bf16x8*)&wh[wb];
                const bf16x8 bm = *(const bf16x8*)&wm[wb];
                const bf16x8 bl = *(const bf16x8*)&wl[wb];
                acc[0][t] = __builtin_amdgcn_mfma_f32_16x16x32_bf16(ah0, bh, acc[0][t], 0, 0, 0);
                acc[0][t] = __builtin_amdgcn_mfma_f32_16x16x32_bf16(ah0, bm, acc[0][t], 0, 0, 0);
                acc[0][t] = __builtin_amdgcn_mfma_f32_16x16x32_bf16(am0, bh, acc[0][t], 0, 0, 0);
                acc[0][t] = __builtin_amdgcn_mfma_f32_16x16x32_bf16(ah0, bl, acc[0][t], 0, 0, 0);
                acc[0][t] = __builtin_amdgcn_mfma_f32_16x16x32_bf16(al0, bh, acc[0][t], 0, 0, 0);
                acc[0][t] = __builtin_amdgcn_mfma_f32_16x16x32_bf16(am0, bm, acc[0][t], 0, 0, 0);
                acc[1][t] = __builtin_amdgcn_mfma_f32_16x16x32_bf16(ah1, bh, acc[1][t], 0, 0, 0);
                acc[1][t] = __builtin_amdgcn_mfma_f32_16x16x32_bf16(ah1, bm, acc[1][t], 0, 0, 0);
                acc[1][t] = __builtin_amdgcn_mfma_f32_16x16x32_bf16(am1, bh, acc[1][t], 0, 0, 0);
                acc[1][t] = __builtin_amdgcn_mfma_f32_16x16x32_bf16(ah1, bl, acc[1][t], 0, 0, 0);
                acc[1][t] = __builtin_amdgcn_mfma_f32_16x16x32_bf16(al1, bh, acc[1][t], 0, 0, 0);
                acc[1][t] = __builtin_amdgcn_mfma_f32_16x16x32_bf16(am1, bm, acc[1][t], 0, 0, 0);
            }
        }
    };

    // barrier-free K-loop, ping-pong A prefetch
    loadA(0, ca);
    #pragma unroll 1
    for (int ch = 0; ch < NCH; ch += 2) {
        loadA(ch + 1, pa);
        compute(ch, ca);
        if (ch + 2 < NCH) loadA(ch + 2, ca);
        compute(ch + 1, pa);
    }

    // ---- in-block k-reduction (only barriers in the kernel) ----
    #pragma unroll
    for (int m = 0; m < 2; ++m)
        #pragma unroll
        for (int t = 0; t < 4; ++t)
            #pragma unroll
            for (int r = 0; r < 4; ++r)
                red[w][m * 16 + lq * 4 + r][t * 16 + l15] = acc[m][t][r];
    __syncthreads();

    {
        const int f = tid * 8;             // 256 threads x 8 floats = 32x64
        const float* rp = &red[0][0][0];
        f32x4 v0 = *(const f32x4*)&rp[f];
        f32x4 v1 = *(const f32x4*)&rp[f + 4];
        #pragma unroll
        for (int ww = 1; ww < 4; ++ww) {
            const f32x4 u0 = *(const f32x4*)&rp[ww * (TM * E_DIM) + f];
            const f32x4 u1 = *(const f32x4*)&rp[ww * (TM * E_DIM) + f + 4];
            v0 += u0; v1 += u1;
        }
        const int e0 = f & 63;
        v0 += *(const f32x4*)&bias[e0];
        v1 += *(const f32x4*)&bias[e0 + 4];
        *(f32x4*)&fin[f]     = v0;
        *(f32x4*)&fin[f + 4] = v1;
    }
    __syncthreads();

    float* out_idx = out;
    float* out_val = out + (size_t)nTok * 2;
    float* sc      = out + (size_t)nTok * 4;

    // ---- fused top-2 + softmax (4 lanes per token, threads 0..127) ----
    if (tid < TM * 4) {
        const int tok = tid >> 2;
        const int g   = tid & 3;
        float v[16];
        #pragma unroll
        for (int j = 0; j < 4; ++j) {
            const f32x4 x = *(const f32x4*)&fin[tok * E_DIM + g * 16 + j * 4];
            v[j*4+0] = x[0]; v[j*4+1] = x[1]; v[j*4+2] = x[2]; v[j*4+3] = x[3];
        }
        float b1 = -INFINITY, b2 = -INFINITY;
        int i1 = 0, i2 = 0;
        #pragma unroll
        for (int j = 0; j < 16; ++j) {
            const float x = v[j];
            const int idx = g * 16 + j;
            if (x > b1)      { b2 = b1; i2 = i1; b1 = x; i1 = idx; }
            else if (x > b2) { b2 = x; i2 = idx; }
        }
        #pragma unroll
        for (int d = 1; d <= 2; d <<= 1) {
            const float ob1 = __shfl_xor(b1, d);
            const int   oi1 = __shfl_xor(i1, d);
            const float ob2 = __shfl_xor(b2, d);
            const int   oi2 = __shfl_xor(i2, d);
            if (ob1 > b1 || (ob1 == b1 && oi1 < i1)) {
                if (b1 > ob2 || (b1 == ob2 && i1 < oi2)) { b2 = b1; i2 = i1; }
                else                                     { b2 = ob2; i2 = oi2; }
                b1 = ob1; i1 = oi1;
            } else {
                if (ob1 > b2 || (ob1 == b2 && oi1 < i2)) { b2 = ob1; i2 = oi1; }
            }
        }
        const float m = b1;
        float s = 0.f;
        #pragma unroll
        for (int j = 0; j < 16; ++j) s += __expf(v[j] - m);
        s += __shfl_xor(s, 1);
        s += __shfl_xor(s, 2);
        const float inv = 1.f / s;
        if (g == 0) {
            const size_t gt = (size_t)(tb + tok);
            out_idx[gt * 2 + 0] = (float)i1;
            out_idx[gt * 2 + 1] = (float)i2;
            out_val[gt * 2 + 0] = inv;                      // exp(b1-m)=1
            out_val[gt * 2 + 1] = __expf(b2 - m) * inv;
            s_m[tok] = m;
            s_inv[tok] = inv;
        }
    }
    __syncthreads();

    // ---- coalesced scores write ----
    {
        const int f   = tid * 8;
        const int tok = f >> 6;
        const float m = s_m[tok], inv = s_inv[tok];
        f32x4 o0, o1;
        #pragma unroll
        for (int j = 0; j < 4; ++j) o0[j] = __expf(fin[f + j] - m) * inv;
        #pragma unroll
        for (int j = 0; j < 4; ++j) o1[j] = __expf(fin[f + 4 + j] - m) * inv;
        *(f32x4*)&sc[(size_t)tb * E_DIM + f]     = o0;
        *(f32x4*)&sc[(size_t)tb * E_DIM + f + 4] = o1;
    }
}

extern "C" void kernel_launch(void* const* d_in, const int* in_sizes, int n_in,
                              void* d_out, int out_size, void* d_ws, size_t ws_size,
                              hipStream_t stream) {
    const float* hs = (const float*)d_in[0];
    const float* W  = (const float*)d_in[1];
    const float* b  = (const float*)d_in[2];
    float* out = (float*)d_out;
    const int nTok = in_sizes[0] / D_DIM;   // 16384

    short* wsp = (short*)d_ws;              // 3 x 512 KB level arrays
    short* wh = wsp;
    short* wm = wsp + E_DIM * D_DIM;
    short* wl = wsp + 2 * E_DIM * D_DIM;

    presplit<<<dim3(E_DIM * D_DIM / 1024), dim3(256), 0, stream>>>(W, wh, wm, wl);
    router_main<<<dim3(nTok / TM), dim3(256), 0, stream>>>(hs, wh, wm, wl, b, out, nTok);
}